// Round 3
// baseline (249.676 us; speedup 1.0000x reference)
//
#include <hip/hip_runtime.h>

// LSTM (B=8192, T=512, H=5) + MLP 5->32->32->5, fp32.
// 8 lanes per row (lane j<5 owns hidden unit j), 8 rows/wave, 1024 one-wave
// blocks = 1 wave/SIMD. h-broadcast via DPP row shifts (VALU pipe, no
// lgkmcnt). DPP semantics (per AMD cross-lane docs / scan idiom):
//   row_shr:N -> dst[i] = src[i-N]   (data moves to higher lanes)
//   row_shl:N -> dst[i] = src[i+N]   (data moves to lower lanes)
// so hc[t] = h_{j+t-4}, and w9[g][t] = W_hh[g*5+j][j+t-4] (0 outside [0,5)).
// Round-2 had this pairing reversed -> absmax 4.8e-2. Fixed here.

#define LOG2E 1.44269504088896f

__device__ __forceinline__ float hexp2(float x) { return __builtin_amdgcn_exp2f(x); }
__device__ __forceinline__ float hrcp(float x)  { return __builtin_amdgcn_rcpf(x); }

// exp2->Inf->rcp->0 saturates correctly, no clamp needed (inputs finite).
__device__ __forceinline__ float fsig(float z) {
  return hrcp(1.0f + hexp2(z * -LOG2E));
}
__device__ __forceinline__ float ftanh(float z) {
  return fmaf(-2.0f, hrcp(hexp2(z * (2.0f * LOG2E)) + 1.0f), 1.0f);
}

template<int CTRL>
__device__ __forceinline__ float dppf(float x) {
  int r = __builtin_amdgcn_update_dpp(0, __builtin_bit_cast(int, x),
                                      CTRL, 0xF, 0xF, true);
  return __builtin_bit_cast(float, r);
}

// component extract with compile-time-foldable index (post-unroll)
__device__ __forceinline__ float sget(const float4* b, int i) {
  float4 v = b[i >> 2];
  switch (i & 3) { case 0: return v.x; case 1: return v.y;
                   case 2: return v.z; default: return v.w; }
}

constexpr int TT = 512;
constexpr int HD = 5;
constexpr int RPB = 8;    // rows per block (8 lanes each, one wave)

__global__ __launch_bounds__(64, 1) void lstm_mlp_kernel(
    const float* __restrict__ x,   const float* __restrict__ Wih,
    const float* __restrict__ Whh, const float* __restrict__ bih,
    const float* __restrict__ bhh, const float* __restrict__ W1,
    const float* __restrict__ b1,  const float* __restrict__ W2,
    const float* __restrict__ b2,  const float* __restrict__ W3,
    const float* __restrict__ b3,  float* __restrict__ out, int B)
{
  const int lane = threadIdx.x;
  const int grp  = lane >> 3;          // row within block (0..7)
  const int j    = lane & 7;           // unit owned (valid if j<5)
  const int row  = blockIdx.x * RPB + grp;
  const bool act = (j < 5) && (row < B);
  const int jj   = (j < 5) ? j : 0;    // safe row index for weight loads

  __shared__ float sh[RPB][6];
  __shared__ float s1[RPB][36];
  __shared__ float s2[RPB][36];

  // ---- per-lane weights ----
  float wi[4][5], bsum[4], w9[4][9];
#pragma unroll
  for (int g = 0; g < 4; ++g) {
#pragma unroll
    for (int k = 0; k < 5; ++k) wi[g][k] = Wih[(g * 5 + jj) * 5 + k];
    bsum[g] = bih[g * 5 + jj] + bhh[g * 5 + jj];
    // hc[t] = h_{j+t-4}  (row_shr:N gives src[i-N]); pair weight accordingly
#pragma unroll
    for (int t = 0; t < 9; ++t) {
      int k = j + t - 4;
      w9[g][t] = (j < 5 && k >= 0 && k < 5) ? Whh[(g * 5 + j) * 5 + k] : 0.0f;
    }
  }

  const float* xrow = x + (size_t)((row < B) ? row : 0) * (TT * HD);

  float c = 0.0f;
  float hc[9];                          // shifted h copies (all start 0)
#pragma unroll
  for (int t = 0; t < 9; ++t) hc[t] = 0.0f;

  float4 xa[10], xb[10];
  {
    const float4* p = (const float4*)(xrow);
#pragma unroll
    for (int i = 0; i < 10; ++i) xa[i] = p[i];
  }

  auto load_slab = [&](float4* dst, int t0) {
    const float4* p = (const float4*)(xrow + t0 * HD);
#pragma unroll
    for (int i = 0; i < 10; ++i) dst[i] = p[i];
  };

  auto step = [&](const float4* xs, int s) {
    float z[4];
#pragma unroll
    for (int g = 0; g < 4; ++g) {
      // x-part + bias (off the h critical path)
      float a0 = bsum[g];
#pragma unroll
      for (int k = 0; k < 5; ++k) a0 = fmaf(sget(xs, s * 5 + k), wi[g][k], a0);
      // h-part: two independent partial chains to cut dep latency
      float p0 = 0.0f, p1 = 0.0f;
#pragma unroll
      for (int t = 0; t < 4; ++t) p0 = fmaf(w9[g][t], hc[t], p0);
#pragma unroll
      for (int t = 4; t < 9; ++t) p1 = fmaf(w9[g][t], hc[t], p1);
      z[g] = a0 + p0 + p1;
    }
    float ig = fsig(z[0]);
    float fg = fsig(z[1]);
    float gg = ftanh(z[2]);
    float og = fsig(z[3]);
    c = fmaf(fg, c, ig * gg);
    float hj = og * ftanh(c);
    // broadcast for next step: hc[t] = h_{j+t-4}
    hc[0] = dppf<0x114>(hj);   // row_shr:4 -> src[i-4] = h_{j-4}
    hc[1] = dppf<0x113>(hj);   // row_shr:3 -> h_{j-3}
    hc[2] = dppf<0x112>(hj);   // row_shr:2 -> h_{j-2}
    hc[3] = dppf<0x111>(hj);   // row_shr:1 -> h_{j-1}
    hc[4] = hj;
    hc[5] = dppf<0x101>(hj);   // row_shl:1 -> src[i+1] = h_{j+1}
    hc[6] = dppf<0x102>(hj);   // row_shl:2 -> h_{j+2}
    hc[7] = dppf<0x103>(hj);   // row_shl:3 -> h_{j+3}
    hc[8] = dppf<0x104>(hj);   // row_shl:4 -> h_{j+4}
  };

#pragma unroll 1
  for (int tc = 0; tc < TT; tc += 16) {
    load_slab(xb, tc + 8);               // tc+8 <= 504, always valid
#pragma unroll
    for (int s = 0; s < 8; ++s) step(xa, s);
    if (tc + 16 < TT) load_slab(xa, tc + 16);
#pragma unroll
    for (int s = 0; s < 8; ++s) step(xb, s);
  }
  // xb now holds t = 504..511; x[t=511] = floats 35..39.

  // ---- MLP head (one-time; LDS within a single wave, no barrier needed) --
  if (act) sh[grp][j] = hc[4];          // h_j (last step)
  float in5[5];
#pragma unroll
  for (int k = 0; k < 5; ++k) in5[k] = sh[grp][k] + sget(xb, 35 + k);

  // layer1: 32 outputs, 4 per lane (m = p*8 + j)
#pragma unroll
  for (int p = 0; p < 4; ++p) {
    int m = p * 8 + j;
    float acc = b1[m];
#pragma unroll
    for (int k = 0; k < 5; ++k) acc = fmaf(W1[m * 5 + k], in5[k], acc);
    s1[grp][m] = fmaxf(acc, 0.0f);
  }
  float y1[32];
#pragma unroll
  for (int k = 0; k < 32; ++k) y1[k] = s1[grp][k];

  // layer2
#pragma unroll
  for (int p = 0; p < 4; ++p) {
    int m = p * 8 + j;
    float acc = b2[m];
    const float4* w4 = (const float4*)(W2 + m * 32);
#pragma unroll
    for (int k4 = 0; k4 < 8; ++k4) {
      float4 w = w4[k4];
      acc = fmaf(w.x, y1[k4 * 4 + 0], acc);
      acc = fmaf(w.y, y1[k4 * 4 + 1], acc);
      acc = fmaf(w.z, y1[k4 * 4 + 2], acc);
      acc = fmaf(w.w, y1[k4 * 4 + 3], acc);
    }
    s2[grp][m] = fmaxf(acc, 0.0f);
  }
  float y2[32];
#pragma unroll
  for (int k = 0; k < 32; ++k) y2[k] = s2[grp][k];

  // layer3: lanes j<5 write out[row*5+j]
  if (act) {
    float acc = b3[j];
    const float4* w4 = (const float4*)(W3 + jj * 32);
#pragma unroll
    for (int k4 = 0; k4 < 8; ++k4) {
      float4 w = w4[k4];
      acc = fmaf(w.x, y2[k4 * 4 + 0], acc);
      acc = fmaf(w.y, y2[k4 * 4 + 1], acc);
      acc = fmaf(w.z, y2[k4 * 4 + 2], acc);
      acc = fmaf(w.w, y2[k4 * 4 + 3], acc);
    }
    out[row * 5 + j] = acc;
  }
}

extern "C" void kernel_launch(void* const* d_in, const int* in_sizes, int n_in,
                              void* d_out, int out_size, void* d_ws, size_t ws_size,
                              hipStream_t stream) {
  const float* x   = (const float*)d_in[0];
  const float* Wih = (const float*)d_in[1];
  const float* Whh = (const float*)d_in[2];
  const float* bih = (const float*)d_in[3];
  const float* bhh = (const float*)d_in[4];
  const float* W1  = (const float*)d_in[5];
  const float* b1  = (const float*)d_in[6];
  const float* W2  = (const float*)d_in[7];
  const float* b2  = (const float*)d_in[8];
  const float* W3  = (const float*)d_in[9];
  const float* b3  = (const float*)d_in[10];

  int B = in_sizes[0] / (TT * HD);
  int grid = (B + RPB - 1) / RPB;
  hipLaunchKernelGGL(lstm_mlp_kernel, dim3(grid), dim3(64), 0, stream,
                     x, Wih, Whh, bih, bhh, W1, b1, W2, b2, W3, b3,
                     (float*)d_out, B);
}